// Round 13
// baseline (134.431 us; speedup 1.0000x reference)
//
#include <hip/hip_runtime.h>
#include <hip/hip_fp16.h>

#define T_LEN 262144
#define HID 32
#define CHUNK 128                 // live steps per chunk
#define WARM 64                   // warm-up steps (err ~0.8^64≈6e-7; r9/r11/r12-verified)
#define NBLK (T_LEN / CHUNK / 2)  // 1024 blocks, each wave runs 2 chunks

typedef _Float16 half2_t __attribute__((ext_vector_type(2)));

// ---- tiny intrinsic wrappers -------------------------------------------------
__device__ __forceinline__ float rl_f(float v, int lane) {
    return __int_as_float(__builtin_amdgcn_readlane(__float_as_int(v), lane));
}
__device__ __forceinline__ int rl_i(int v, int lane) {
    return __builtin_amdgcn_readlane(v, lane);
}

#if defined(__has_builtin)
#if __has_builtin(__builtin_amdgcn_exp2f)
#define FEXP2(x) __builtin_amdgcn_exp2f(x)
#endif
#endif
#ifndef FEXP2
#define FEXP2(x) exp2f(x)
#endif

__device__ __forceinline__ float frcp(float x) { return __builtin_amdgcn_rcpf(x); }

#if defined(__has_builtin)
#if __has_builtin(__builtin_amdgcn_sched_barrier)
#define SCHED_FENCE() __builtin_amdgcn_sched_barrier(0)
#endif
#endif
#ifndef SCHED_FENCE
#define SCHED_FENCE()
#endif

// packed 2×f16 MAC with f32 accumulate (v_dot2_f32_f16, full-rate VOP3P)
#if defined(__has_builtin) && __has_builtin(__builtin_amdgcn_fdot2)
#define FDOT2(a, b, c) __builtin_amdgcn_fdot2((a), (b), (c), false)
#else
#define FDOT2(a, b, c) fmaf((float)(a).x, (float)(b).x, \
                            fmaf((float)(a).y, (float)(b).y, (c)))
#endif

// quad_perm DPP cross-lane: full-rate VALU. [1,0,3,2]=0xB1 (lane^1), [2,3,0,1]=0x4E (lane^2)
__device__ __forceinline__ int dpp_xor1_i(int v) {
#if defined(__has_builtin) && __has_builtin(__builtin_amdgcn_mov_dpp)
    return __builtin_amdgcn_mov_dpp(v, 0xB1, 0xF, 0xF, true);
#else
    return __builtin_amdgcn_ds_swizzle(v, 0x041F);
#endif
}
__device__ __forceinline__ int dpp_xor2_i(int v) {
#if defined(__has_builtin) && __has_builtin(__builtin_amdgcn_mov_dpp)
    return __builtin_amdgcn_mov_dpp(v, 0x4E, 0xF, 0xF, true);
#else
    return __builtin_amdgcn_ds_swizzle(v, 0x081F);
#endif
}
__device__ __forceinline__ float dpp_xor1_f(float v) {
    return __int_as_float(dpp_xor1_i(__float_as_int(v)));
}
__device__ __forceinline__ float dpp_xor2_f(float v) {
    return __int_as_float(dpp_xor2_i(__float_as_int(v)));
}

// pack two f32 -> f16x2 in ONE instruction (v_cvt_pkrtz_f16_f32)
__device__ __forceinline__ int pack_rtz(float a, float b) {
#if defined(__has_builtin) && __has_builtin(__builtin_amdgcn_cvt_pkrtz)
    return __builtin_bit_cast(int, __builtin_amdgcn_cvt_pkrtz(a, b));
#else
    unsigned short ua = __builtin_bit_cast(unsigned short, (_Float16)a);
    unsigned short ub = __builtin_bit_cast(unsigned short, (_Float16)b);
    return (int)((unsigned int)ua | ((unsigned int)ub << 16));
#endif
}

#define L2E 1.4426950408889634f
#define KN2 (-2.0f * L2E)

// ---- repetition macros -------------------------------------------------------
#define REP16(M) M(0) M(1) M(2) M(3) M(4) M(5) M(6) M(7) \
                 M(8) M(9) M(10) M(11) M(12) M(13) M(14) M(15)

__device__ __forceinline__ unsigned int pack_f16(float a, float b) {
    unsigned short ua = __builtin_bit_cast(unsigned short, (_Float16)a);
    unsigned short ub = __builtin_bit_cast(unsigned short, (_Float16)b);
    return (unsigned int)ua | ((unsigned int)ub << 16);
}

// weight pair p: columns 2p,2p+1 of rows rowA / rowB, prescaled then f16-packed
// (shared by both chunks — same lane->row mapping)
#define DECLW(p) unsigned int wp0_##p, wp1_##p;
#define LOADW(p) \
    wp0_##p = pack_f16(W_hh[rowA * HID + 2 * p] * sA, W_hh[rowA * HID + 2 * p + 1] * sA); \
    wp1_##p = pack_f16(W_hh[rowB * HID + 2 * p] * sB, W_hh[rowB * HID + 2 * p + 1] * sB);

// Zero-instruction register pin (r3/r4 lesson)
#define PIN8(a,b,c,d,e,f,g,h_) \
    asm("" : "+v"(a), "+v"(b), "+v"(c), "+v"(d), \
             "+v"(e), "+v"(f), "+v"(g), "+v"(h_));
#define PIN_ALL \
    PIN8(wp0_0,wp0_1,wp0_2,wp0_3,wp0_4,wp0_5,wp0_6,wp0_7) \
    PIN8(wp0_8,wp0_9,wp0_10,wp0_11,wp0_12,wp0_13,wp0_14,wp0_15) \
    PIN8(wp1_0,wp1_1,wp1_2,wp1_3,wp1_4,wp1_5,wp1_6,wp1_7) \
    PIN8(wp1_8,wp1_9,wp1_10,wp1_11,wp1_12,wp1_13,wp1_14,wp1_15) \
    PIN8(wi00,wi01,wi02,wi10,wi11,wi12,bb0,bb1)

// broadcast packed h pair p of chunk S from lane 4p+1
#define RLHA(p) const int hpA_##p = rl_i(h2A, 4 * p + 1);
#define RLHB(p) const int hpB_##p = rl_i(h2B, 4 * p + 1);

// dual-chunk MAC: one weight pair feeds both chunks (A then B), 2 acc
// chains per (chunk,row) -> 8 independent dep streams of depth 8
#define MACD(p, q) { \
    const half2_t hA_##p = __builtin_bit_cast(half2_t, hpA_##p); \
    const half2_t hB_##p = __builtin_bit_cast(half2_t, hpB_##p); \
    a0##q##A = FDOT2(__builtin_bit_cast(half2_t, wp0_##p), hA_##p, a0##q##A); \
    a0##q##B = FDOT2(__builtin_bit_cast(half2_t, wp0_##p), hB_##p, a0##q##B); \
    a1##q##A = FDOT2(__builtin_bit_cast(half2_t, wp1_##p), hA_##p, a1##q##A); \
    a1##q##B = FDOT2(__builtin_bit_cast(half2_t, wp1_##p), hB_##p, a1##q##B); }

#define MAC_ALL \
    MACD(0,a) MACD(1,b) MACD(2,a) MACD(3,b) MACD(4,a) MACD(5,b) \
    MACD(6,a) MACD(7,b) MACD(8,a) MACD(9,b) MACD(10,a) MACD(11,b) \
    MACD(12,a) MACD(13,b) MACD(14,a) MACD(15,b)

// ---- fused dual-chunk scan + output GEMV -------------------------------------
// Each 64-thread block (one wave) runs TWO independent chunks: cA = 2b,
// cB = 2b+1. Weights live once in VGPRs; state (c2,h,h2,x-buffers) is
// duplicated. The two serial chains interleave WITHIN the instruction stream,
// filling each other's dependency stalls deterministically (r12 showed
// cross-wave interleave saturates only 74% of VALU issue; in-wave ILP is the
// reliable version of the same idea).
//
// Chunks cb>0 warm up WARM steps from (h,c)=(0,0) (contraction: err ~0.8^64
// ~ 6e-7; verified r9-r12: absmax floor is f16 weight quantization). Chunk 0
// runs all 3 groups live from t=0 (exact); its 3rd group [128,192) overlaps
// chunk 1's live range — same wave, A-store precedes B-store in program
// order, values agree to ~1e-12: benign. Blocks fully independent (G16-safe).
//
// QUAD-LOCAL gate mapping (r8) + prescaled f16 weights + KN2-folded tanh.
// FUSED OUTPUT (r10): per-chunk stage[64][33] (bank-clean), one coalesced
// 256 B store per chunk per 64 steps.
__global__
__attribute__((amdgpu_flat_work_group_size(64, 64), amdgpu_waves_per_eu(1, 1)))
void lstm_scan(
    const float* __restrict__ x,      // [T,3]
    const float* __restrict__ W_ih,   // [128,3]
    const float* __restrict__ W_hh,   // [128,32]
    const float* __restrict__ b_ih,   // [128]
    const float* __restrict__ b_hh,   // [128]
    const float* __restrict__ W_lin,  // [1,32]
    const float* __restrict__ b_lin,  // [1]
    float* __restrict__ out)          // [T]
{
    // LDS = 16896 (2 stages) + 24064 (guard) = 40960 B -> 4 blocks/CU,
    // 1 wave/EU residency; waves_per_eu(1,1) -> full RA budget (r4 mechanism).
    __shared__ float stage[2][64 * 33];
    __shared__ float lds_guard[6016];
    ((volatile float*)lds_guard)[threadIdx.x] = 0.0f;

    const int l = threadIdx.x;        // 0..63
    const int u = l >> 1;
    const bool even = (l & 1) == 0;
    const int rowA = even ? u : (HID + u);                  // i_u | f_u (sigmoid)
    const int rowB = even ? (2 * HID + u) : (3 * HID + u);  // g_u | o_u
    const float sA = -L2E;
    const float sB = even ? KN2 : -L2E;
    const float m1 = even ? (2.0f * KN2) : 1.0f;
    const float d1 = even ? (-KN2) : 0.0f;

    REP16(DECLW)
    REP16(LOADW)

    float wi00 = W_ih[rowA * 3 + 0] * sA, wi01 = W_ih[rowA * 3 + 1] * sA,
          wi02 = W_ih[rowA * 3 + 2] * sA;
    float wi10 = W_ih[rowB * 3 + 0] * sB, wi11 = W_ih[rowB * 3 + 1] * sB,
          wi12 = W_ih[rowB * 3 + 2] * sB;
    float bb0 = (b_ih[rowA] + b_hh[rowA]) * sA;
    float bb1 = (b_ih[rowB] + b_hh[rowB]) * sB;

    const float wl = even ? 0.0f : W_lin[u];
    const float bl = b_lin[0];

    // chunk bases: 3 groups of 64 each; group g covers base + [64g, 64g+64)
    const int cA = blockIdx.x * 2;
    const int cB = cA + 1;
    const int baseA = (cA == 0) ? 0 : (cA * CHUNK - WARM);
    const int baseB = cB * CHUNK - WARM;
    const bool a0live = (cA == 0);    // chunk 0: all 3 groups live (exact scan)

    float c2A = 0.0f, hA = 0.0f; int h2A = 0;
    float c2B = 0.0f, hB = 0.0f; int h2B = 0;

    // x double-buffers
    float xaA, xbA, xcA, xaB, xbB, xcB;
    {
        const float* pA = x + (baseA + l) * 3;
        xaA = pA[0]; xbA = pA[1]; xcA = pA[2];
        const float* pB = x + (baseB + l) * 3;
        xaB = pB[0]; xbB = pB[1]; xcB = pB[2];
    }

    for (int g = 0; g < 3; ++g) {
        PIN_ALL

        const int gn = (g == 2) ? 0 : (g + 1);   // dummy re-prefetch on last
        const float* pA = x + (baseA + gn * 64 + l) * 3;
        float xnaA = pA[0], xnbA = pA[1], xncA = pA[2];
        const float* pB = x + (baseB + gn * 64 + l) * 3;
        float xnaB = pB[0], xnbB = pB[1], xncB = pB[2];

        const bool liveA = a0live || (g >= 1);
        const bool liveB = (g >= 1);

#pragma unroll 4
        for (int tu = 0; tu < 64; ++tu) {
            // ---- broadcast batch: both x rows + 32 packed h pairs ----------
            const float xs0A = rl_f(xaA, tu), xs1A = rl_f(xbA, tu), xs2A = rl_f(xcA, tu);
            const float xs0B = rl_f(xaB, tu), xs1B = rl_f(xbB, tu), xs2B = rl_f(xcB, tu);
            REP16(RLHA)
            REP16(RLHB)
            SCHED_FENCE();

            // ---- x contributions (seed the acc chains) ---------------------
            float a0aA = fmaf(wi00, xs0A, bb0);
            float a0bA = fmaf(wi01, xs1A, wi02 * xs2A);
            float a1aA = fmaf(wi10, xs0A, bb1);
            float a1bA = fmaf(wi11, xs1A, wi12 * xs2A);
            float a0aB = fmaf(wi00, xs0B, bb0);
            float a0bB = fmaf(wi01, xs1B, wi02 * xs2B);
            float a1aB = fmaf(wi10, xs0B, bb1);
            float a1bB = fmaf(wi11, xs1B, wi12 * xs2B);

            // ---- dual recurrent matvec (8 independent dot2 chains) ---------
            MAC_ALL

            const float S0A = a0aA + a0bA;
            const float S1A = a1aA + a1bA;
            const float S0B = a0aB + a0bB;
            const float S1B = a1aB + a1bB;

            // ---- activations (A and B independent -> compiler interleaves) --
            const float g0A = frcp(1.0f + FEXP2(S0A));
            const float g1A = fmaf(frcp(1.0f + FEXP2(S1A)), m1, d1);
            const float g0B = frcp(1.0f + FEXP2(S0B));
            const float g1B = fmaf(frcp(1.0f + FEXP2(S1B)), m1, d1);

            // ---- chains ----------------------------------------------------
            const float igKA = g0A * g1A;
            const float igKB = g0B * g1B;
            const float tA_ = dpp_xor1_f(igKA);
            const float tB_ = dpp_xor1_f(igKB);
            c2A = fmaf(g0A, c2A, tA_);
            c2B = fmaf(g0B, c2B, tB_);
            const float tcA = fmaf(frcp(1.0f + FEXP2(c2A)), 2.0f, -1.0f);
            const float tcB = fmaf(frcp(1.0f + FEXP2(c2B)), 2.0f, -1.0f);
            hA = g1A * tcA;
            hB = g1B * tcB;

            // ---- packed-f16 h pairs ---------------------------------------
            const float hnA = dpp_xor2_f(hA);
            const float hnB = dpp_xor2_f(hB);
            h2A = pack_rtz(hA, hnA);
            h2B = pack_rtz(hB, hnB);

            // ---- fused output staging (live, odd lanes) --------------------
            if (liveA && !even) stage[0][tu * 33 + u] = hA * wl;
            if (liveB && !even) stage[1][tu * 33 + u] = hB * wl;
        }

        // ---- per-group output reduction + coalesced stores -----------------
        if (liveA) {
            float s = bl;
            const float* row = &stage[0][l * 33];
#pragma unroll
            for (int j = 0; j < HID; ++j) s += row[j];
            out[baseA + g * 64 + l] = s;
        }
        if (liveB) {                       // after A: program-order overwrite
            float s = bl;
            const float* row = &stage[1][l * 33];
#pragma unroll
            for (int j = 0; j < HID; ++j) s += row[j];
            out[baseB + g * 64 + l] = s;
        }

        xaA = xnaA; xbA = xnbA; xcA = xncA;
        xaB = xnaB; xbB = xnbB; xcB = xncB;
    }
}

extern "C" void kernel_launch(void* const* d_in, const int* in_sizes, int n_in,
                              void* d_out, int out_size, void* d_ws, size_t ws_size,
                              hipStream_t stream) {
    const float* x = (const float*)d_in[0];
    const float* W_ih = (const float*)d_in[1];
    const float* W_hh = (const float*)d_in[2];
    const float* b_ih = (const float*)d_in[3];
    const float* b_hh = (const float*)d_in[4];
    const float* W_lin = (const float*)d_in[5];
    const float* b_lin = (const float*)d_in[6];
    float* out = (float*)d_out;
    (void)d_ws; (void)ws_size;

    hipLaunchKernelGGL(lstm_scan, dim3(NBLK), dim3(64), 0, stream,
                       x, W_ih, W_hh, b_ih, b_hh, W_lin, b_lin, out);
}

// Round 14
// 123.631 us; speedup vs baseline: 1.0874x; 1.0874x over previous
//
#include <hip/hip_runtime.h>
#include <hip/hip_fp16.h>

#define T_LEN 262144
#define HID 32
#define CHUNK 128                 // live steps per wave
#define WARM 32                   // warm-up steps (partial group; err ~rho^32 <~ 1e-3)
#define NBLK (T_LEN / CHUNK / 2)  // 1024 blocks x 2 waves -> 2048 chunks

typedef _Float16 half2_t __attribute__((ext_vector_type(2)));

// ---- tiny intrinsic wrappers -------------------------------------------------
__device__ __forceinline__ float rl_f(float v, int lane) {
    return __int_as_float(__builtin_amdgcn_readlane(__float_as_int(v), lane));
}
__device__ __forceinline__ int rl_i(int v, int lane) {
    return __builtin_amdgcn_readlane(v, lane);
}

#if defined(__has_builtin)
#if __has_builtin(__builtin_amdgcn_exp2f)
#define FEXP2(x) __builtin_amdgcn_exp2f(x)
#endif
#endif
#ifndef FEXP2
#define FEXP2(x) exp2f(x)
#endif

__device__ __forceinline__ float frcp(float x) { return __builtin_amdgcn_rcpf(x); }

#if defined(__has_builtin)
#if __has_builtin(__builtin_amdgcn_sched_barrier)
#define SCHED_FENCE() __builtin_amdgcn_sched_barrier(0)
#endif
#endif
#ifndef SCHED_FENCE
#define SCHED_FENCE()
#endif

// packed 2×f16 MAC with f32 accumulate (v_dot2_f32_f16, full-rate VOP3P)
#if defined(__has_builtin) && __has_builtin(__builtin_amdgcn_fdot2)
#define FDOT2(a, b, c) __builtin_amdgcn_fdot2((a), (b), (c), false)
#else
#define FDOT2(a, b, c) fmaf((float)(a).x, (float)(b).x, \
                            fmaf((float)(a).y, (float)(b).y, (c)))
#endif

// quad_perm DPP cross-lane: full-rate VALU. [1,0,3,2]=0xB1 (lane^1), [2,3,0,1]=0x4E (lane^2)
__device__ __forceinline__ int dpp_xor1_i(int v) {
#if defined(__has_builtin) && __has_builtin(__builtin_amdgcn_mov_dpp)
    return __builtin_amdgcn_mov_dpp(v, 0xB1, 0xF, 0xF, true);
#else
    return __builtin_amdgcn_ds_swizzle(v, 0x041F);
#endif
}
__device__ __forceinline__ int dpp_xor2_i(int v) {
#if defined(__has_builtin) && __has_builtin(__builtin_amdgcn_mov_dpp)
    return __builtin_amdgcn_mov_dpp(v, 0x4E, 0xF, 0xF, true);
#else
    return __builtin_amdgcn_ds_swizzle(v, 0x081F);
#endif
}
__device__ __forceinline__ float dpp_xor1_f(float v) {
    return __int_as_float(dpp_xor1_i(__float_as_int(v)));
}
__device__ __forceinline__ float dpp_xor2_f(float v) {
    return __int_as_float(dpp_xor2_i(__float_as_int(v)));
}

// pack two f32 -> f16x2 in ONE instruction (v_cvt_pkrtz_f16_f32)
__device__ __forceinline__ int pack_rtz(float a, float b) {
#if defined(__has_builtin) && __has_builtin(__builtin_amdgcn_cvt_pkrtz)
    return __builtin_bit_cast(int, __builtin_amdgcn_cvt_pkrtz(a, b));
#else
    unsigned short ua = __builtin_bit_cast(unsigned short, (_Float16)a);
    unsigned short ub = __builtin_bit_cast(unsigned short, (_Float16)b);
    return (int)((unsigned int)ua | ((unsigned int)ub << 16));
#endif
}

#define L2E 1.4426950408889634f
#define KN2 (-2.0f * L2E)

// ---- repetition macros -------------------------------------------------------
#define REP16(M) M(0) M(1) M(2) M(3) M(4) M(5) M(6) M(7) \
                 M(8) M(9) M(10) M(11) M(12) M(13) M(14) M(15)

__device__ __forceinline__ unsigned int pack_f16(float a, float b) {
    unsigned short ua = __builtin_bit_cast(unsigned short, (_Float16)a);
    unsigned short ub = __builtin_bit_cast(unsigned short, (_Float16)b);
    return (unsigned int)ua | ((unsigned int)ub << 16);
}

// weight pair p: columns 2p,2p+1 of rows rowA / rowB, prescaled then f16-packed
#define DECLW(p) unsigned int wp0_##p, wp1_##p;
#define LOADW(p) \
    wp0_##p = pack_f16(W_hh[rowA * HID + 2 * p] * sA, W_hh[rowA * HID + 2 * p + 1] * sA); \
    wp1_##p = pack_f16(W_hh[rowB * HID + 2 * p] * sB, W_hh[rowB * HID + 2 * p + 1] * sB);

// Zero-instruction register pin (r3/r4 lesson): keeps the packed weights
// loop-carried in VGPRs under the raised RA budget.
#define PIN8(a,b,c,d,e,f,g,h_) \
    asm("" : "+v"(a), "+v"(b), "+v"(c), "+v"(d), \
             "+v"(e), "+v"(f), "+v"(g), "+v"(h_));
#define PIN_ALL \
    PIN8(wp0_0,wp0_1,wp0_2,wp0_3,wp0_4,wp0_5,wp0_6,wp0_7) \
    PIN8(wp0_8,wp0_9,wp0_10,wp0_11,wp0_12,wp0_13,wp0_14,wp0_15) \
    PIN8(wp1_0,wp1_1,wp1_2,wp1_3,wp1_4,wp1_5,wp1_6,wp1_7) \
    PIN8(wp1_8,wp1_9,wp1_10,wp1_11,wp1_12,wp1_13,wp1_14,wp1_15) \
    PIN8(wi00,wi01,wi02,wi10,wi11,wi12,bb0,bb1)

// broadcast packed h pair p from lane 4p+1 (h2 = {h[2p],h[2p+1]} lives there)
#define RLH(p) const int hp_##p = rl_i(h2, 4 * p + 1);
// two dot2 per pair (rows rowA,rowB); 4 independent accumulator chains
#define MACP(p, A, B) { \
    const half2_t hh_##p = __builtin_bit_cast(half2_t, hp_##p); \
    A = FDOT2(__builtin_bit_cast(half2_t, wp0_##p), hh_##p, A); \
    B = FDOT2(__builtin_bit_cast(half2_t, wp1_##p), hh_##p, B); }

#define MAC_ALL \
    MACP(0,a0a,a1a) MACP(1,a0b,a1b) MACP(2,a0c,a1c) MACP(3,a0d,a1d) \
    MACP(4,a0a,a1a) MACP(5,a0b,a1b) MACP(6,a0c,a1c) MACP(7,a0d,a1d) \
    MACP(8,a0a,a1a) MACP(9,a0b,a1b) MACP(10,a0c,a1c) MACP(11,a0d,a1d) \
    MACP(12,a0a,a1a) MACP(13,a0b,a1b) MACP(14,a0c,a1c) MACP(15,a0d,a1d)

// One LSTM step consuming x row TU of buffers (XA,XB,XC). Updates c2/h/h2.
// DO_STAGE: statement executed with the fresh h (staging), or empty for warm.
#define STEP(XA, XB, XC, TU, DO_STAGE) do { \
    const float xs0 = rl_f(XA, TU), xs1 = rl_f(XB, TU), xs2 = rl_f(XC, TU); \
    REP16(RLH) \
    SCHED_FENCE(); \
    float a0a = fmaf(wi00, xs0, bb0); \
    float a0b = wi01 * xs1; \
    float a0c = wi02 * xs2; \
    float a0d = 0.0f; \
    float a1a = fmaf(wi10, xs0, bb1); \
    float a1b = wi11 * xs1; \
    float a1c = wi12 * xs2; \
    float a1d = 0.0f; \
    MAC_ALL \
    const float S0 = (a0a + a0b) + (a0c + a0d); \
    const float S1 = (a1a + a1b) + (a1c + a1d); \
    const float g0 = frcp(1.0f + FEXP2(S0));            /* sig(i) | sig(f) */ \
    const float rr = frcp(1.0f + FEXP2(S1)); \
    const float g1 = fmaf(rr, m1, d1);                  /* KN2*tanh(g) | sig(o) */ \
    const float igK = g0 * g1;                          /* even: KN2*i*g */ \
    const float t_ = dpp_xor1_f(igK);                   /* odd gets even's igK */ \
    c2 = fmaf(g0, c2, t_);                              /* odd: f*c2 + KN2*i*g */ \
    const float tc = fmaf(frcp(1.0f + FEXP2(c2)), 2.0f, -1.0f);  /* tanh(c) */ \
    h = g1 * tc;                                        /* odd: o * tanh(c) */ \
    const float hn = dpp_xor2_f(h); \
    h2 = pack_rtz(h, hn);                               /* f16 pair, lanes 4p+1 */ \
    DO_STAGE \
} while (0);

// ---- fused chunked scan + output GEMV, 2 waves/block, 32-step warm -----------
// Wave w of block b owns chunk cb = 2b+w. Chunks cb>0 warm up WARM=32 steps
// from (h,c)=(0,0) in a dedicated partial group (lanes 0..31 of the x buffer),
// then run 2 live 64-step groups. Contraction: r11 showed WARM=64 absmax
// bit-identical to WARM=128 => warm-64 error <~1e-4 => rho <~0.87; expected
// rho~0.8 gives warm-32 error ~1e-4..1e-3, under the f16 quantization floor.
// Empirical law (r10/r12/r13): per-SIMD throughput ~const at 1 chunk-step /
// ~475 cy regardless of wave/ILP config -> dispatch ~ 50.7us x (1+WARM/CHUNK);
// WARM 64->32 is the remaining lever.
//
// r12 residency config: 128-thr blocks (2 waves), 40960 B LDS -> 4 blocks/CU
// = 2 waves/SIMD; waves_per_eu(1,2) (r11 lesson: max clamps residency).
// QUAD-LOCAL gate mapping (r8) + prescaled f16 weights + KN2-folded tanh.
// FUSED OUTPUT (r10): per-wave stage[64][33] (bank-clean), one coalesced
// 256 B store per 64 live steps.
__global__
__attribute__((amdgpu_flat_work_group_size(128, 128), amdgpu_waves_per_eu(1, 2)))
void lstm_scan(
    const float* __restrict__ x,      // [T,3]
    const float* __restrict__ W_ih,   // [128,3]
    const float* __restrict__ W_hh,   // [128,32]
    const float* __restrict__ b_ih,   // [128]
    const float* __restrict__ b_hh,   // [128]
    const float* __restrict__ W_lin,  // [1,32]
    const float* __restrict__ b_lin,  // [1]
    float* __restrict__ out)          // [T]
{
    // LDS = 16896 (2x stage) + 24064 (guard) = 40960 B -> 4 blocks/CU.
    __shared__ float stage[2][64 * 33];
    __shared__ float lds_guard[6016];
    ((volatile float*)lds_guard)[threadIdx.x] = 0.0f;

    const int wid = threadIdx.x >> 6;     // wave id within block (0,1)
    const int l = threadIdx.x & 63;       // lane 0..63
    const int u = l >> 1;
    const bool even = (l & 1) == 0;
    const int rowA = even ? u : (HID + u);                  // i_u | f_u (sigmoid)
    const int rowB = even ? (2 * HID + u) : (3 * HID + u);  // g_u | o_u
    const float sA = -L2E;
    const float sB = even ? KN2 : -L2E;
    const float m1 = even ? (2.0f * KN2) : 1.0f;
    const float d1 = even ? (-KN2) : 0.0f;

    REP16(DECLW)
    REP16(LOADW)

    float wi00 = W_ih[rowA * 3 + 0] * sA, wi01 = W_ih[rowA * 3 + 1] * sA,
          wi02 = W_ih[rowA * 3 + 2] * sA;
    float wi10 = W_ih[rowB * 3 + 0] * sB, wi11 = W_ih[rowB * 3 + 1] * sB,
          wi12 = W_ih[rowB * 3 + 2] * sB;
    float bb0 = (b_ih[rowA] + b_hh[rowA]) * sA;
    float bb1 = (b_ih[rowB] + b_hh[rowB]) * sB;

    const float wl = even ? 0.0f : W_lin[u];
    const float bl = b_lin[0];

    const int cb = blockIdx.x * 2 + wid;
    const int cstart = cb * CHUNK;

    float c2 = 0.0f;                  // c2 = KN2 * c (valid on odd lanes)
    float h = 0.0f;                   // valid on odd lanes
    int h2 = 0;                       // packed f16 pair, valid on lanes 4p+1
    float* mystage = &stage[wid][0];

    // ---- partial warm group: 32 steps, no stores (skipped for chunk 0) -----
    if (cb != 0) {
        const float* wp = x + (cstart - WARM + l) * 3;   // lanes 0..31 consumed
        float wa = wp[0], wb = wp[1], wc = wp[2];
        PIN_ALL
#pragma unroll 4
        for (int tu = 0; tu < WARM; ++tu) {
            STEP(wa, wb, wc, tu, )
        }
    }

    // ---- 2 live groups of 64 steps -----------------------------------------
    float xa, xb, xc;
    {
        const float* xp = x + (cstart + l) * 3;
        xa = xp[0]; xb = xp[1]; xc = xp[2];
    }

    for (int g = 0; g < 2; ++g) {
        PIN_ALL

        const int tn = (g == 0) ? (cstart + 64) : cstart;  // dummy on last
        const float* xp = x + (tn + l) * 3;
        float xna = xp[0], xnb = xp[1], xnc = xp[2];

#pragma unroll 4
        for (int tu = 0; tu < 64; ++tu) {
            STEP(xa, xb, xc, tu,
                 if (!even) { mystage[tu * 33 + u] = h * wl; })
        }

        // per-group output reduction + coalesced store
        {
            float s = bl;
            const float* row = &mystage[l * 33];        // banks (l+j)%32: clean
#pragma unroll
            for (int j = 0; j < HID; ++j) s += row[j];
            out[cstart + g * 64 + l] = s;               // 64 consecutive floats
        }

        xa = xna; xb = xnb; xc = xnc;
    }
}

extern "C" void kernel_launch(void* const* d_in, const int* in_sizes, int n_in,
                              void* d_out, int out_size, void* d_ws, size_t ws_size,
                              hipStream_t stream) {
    const float* x = (const float*)d_in[0];
    const float* W_ih = (const float*)d_in[1];
    const float* W_hh = (const float*)d_in[2];
    const float* b_ih = (const float*)d_in[3];
    const float* b_hh = (const float*)d_in[4];
    const float* W_lin = (const float*)d_in[5];
    const float* b_lin = (const float*)d_in[6];
    float* out = (float*)d_out;
    (void)d_ws; (void)ws_size;

    hipLaunchKernelGGL(lstm_scan, dim3(NBLK), dim3(128), 0, stream,
                       x, W_ih, W_hh, b_ih, b_hh, W_lin, b_lin, out);
}

// Round 15
// 118.425 us; speedup vs baseline: 1.1352x; 1.0440x over previous
//
#include <hip/hip_runtime.h>
#include <hip/hip_fp16.h>

#define T_LEN 262144
#define HID 32
#define CHUNK 128                 // live steps per wave
#define WARM 16                   // warm-up steps (err ~rho^16 ~ 1e-4, rho~0.6; r9/r11/r14 evidence)
#define NBLK (T_LEN / CHUNK / 2)  // 1024 blocks x 2 waves -> 2048 chunks

typedef _Float16 half2_t __attribute__((ext_vector_type(2)));

// ---- tiny intrinsic wrappers -------------------------------------------------
__device__ __forceinline__ float rl_f(float v, int lane) {
    return __int_as_float(__builtin_amdgcn_readlane(__float_as_int(v), lane));
}
__device__ __forceinline__ int rl_i(int v, int lane) {
    return __builtin_amdgcn_readlane(v, lane);
}

#if defined(__has_builtin)
#if __has_builtin(__builtin_amdgcn_exp2f)
#define FEXP2(x) __builtin_amdgcn_exp2f(x)
#endif
#endif
#ifndef FEXP2
#define FEXP2(x) exp2f(x)
#endif

__device__ __forceinline__ float frcp(float x) { return __builtin_amdgcn_rcpf(x); }

#if defined(__has_builtin)
#if __has_builtin(__builtin_amdgcn_sched_barrier)
#define SCHED_FENCE() __builtin_amdgcn_sched_barrier(0)
#endif
#endif
#ifndef SCHED_FENCE
#define SCHED_FENCE()
#endif

// packed 2×f16 MAC with f32 accumulate (v_dot2_f32_f16, full-rate VOP3P)
#if defined(__has_builtin) && __has_builtin(__builtin_amdgcn_fdot2)
#define FDOT2(a, b, c) __builtin_amdgcn_fdot2((a), (b), (c), false)
#else
#define FDOT2(a, b, c) fmaf((float)(a).x, (float)(b).x, \
                            fmaf((float)(a).y, (float)(b).y, (c)))
#endif

// quad_perm DPP cross-lane: full-rate VALU. [1,0,3,2]=0xB1 (lane^1), [2,3,0,1]=0x4E (lane^2)
__device__ __forceinline__ int dpp_xor1_i(int v) {
#if defined(__has_builtin) && __has_builtin(__builtin_amdgcn_mov_dpp)
    return __builtin_amdgcn_mov_dpp(v, 0xB1, 0xF, 0xF, true);
#else
    return __builtin_amdgcn_ds_swizzle(v, 0x041F);
#endif
}
__device__ __forceinline__ int dpp_xor2_i(int v) {
#if defined(__has_builtin) && __has_builtin(__builtin_amdgcn_mov_dpp)
    return __builtin_amdgcn_mov_dpp(v, 0x4E, 0xF, 0xF, true);
#else
    return __builtin_amdgcn_ds_swizzle(v, 0x081F);
#endif
}
__device__ __forceinline__ float dpp_xor1_f(float v) {
    return __int_as_float(dpp_xor1_i(__float_as_int(v)));
}
__device__ __forceinline__ float dpp_xor2_f(float v) {
    return __int_as_float(dpp_xor2_i(__float_as_int(v)));
}

// pack two f32 -> f16x2 in ONE instruction (v_cvt_pkrtz_f16_f32)
__device__ __forceinline__ int pack_rtz(float a, float b) {
#if defined(__has_builtin) && __has_builtin(__builtin_amdgcn_cvt_pkrtz)
    return __builtin_bit_cast(int, __builtin_amdgcn_cvt_pkrtz(a, b));
#else
    unsigned short ua = __builtin_bit_cast(unsigned short, (_Float16)a);
    unsigned short ub = __builtin_bit_cast(unsigned short, (_Float16)b);
    return (int)((unsigned int)ua | ((unsigned int)ub << 16));
#endif
}

#define L2E 1.4426950408889634f
#define KN2 (-2.0f * L2E)

// ---- repetition macros -------------------------------------------------------
#define REP16(M) M(0) M(1) M(2) M(3) M(4) M(5) M(6) M(7) \
                 M(8) M(9) M(10) M(11) M(12) M(13) M(14) M(15)

__device__ __forceinline__ unsigned int pack_f16(float a, float b) {
    unsigned short ua = __builtin_bit_cast(unsigned short, (_Float16)a);
    unsigned short ub = __builtin_bit_cast(unsigned short, (_Float16)b);
    return (unsigned int)ua | ((unsigned int)ub << 16);
}

// weight pair p: columns 2p,2p+1 of rows rowA / rowB, prescaled then f16-packed
#define DECLW(p) unsigned int wp0_##p, wp1_##p;
#define LOADW(p) \
    wp0_##p = pack_f16(W_hh[rowA * HID + 2 * p] * sA, W_hh[rowA * HID + 2 * p + 1] * sA); \
    wp1_##p = pack_f16(W_hh[rowB * HID + 2 * p] * sB, W_hh[rowB * HID + 2 * p + 1] * sB);

// Zero-instruction register pin (r3/r4 lesson): keeps the packed weights
// loop-carried in VGPRs under the raised RA budget.
#define PIN8(a,b,c,d,e,f,g,h_) \
    asm("" : "+v"(a), "+v"(b), "+v"(c), "+v"(d), \
             "+v"(e), "+v"(f), "+v"(g), "+v"(h_));
#define PIN_ALL \
    PIN8(wp0_0,wp0_1,wp0_2,wp0_3,wp0_4,wp0_5,wp0_6,wp0_7) \
    PIN8(wp0_8,wp0_9,wp0_10,wp0_11,wp0_12,wp0_13,wp0_14,wp0_15) \
    PIN8(wp1_0,wp1_1,wp1_2,wp1_3,wp1_4,wp1_5,wp1_6,wp1_7) \
    PIN8(wp1_8,wp1_9,wp1_10,wp1_11,wp1_12,wp1_13,wp1_14,wp1_15) \
    PIN8(wi00,wi01,wi02,wi10,wi11,wi12,bb0,bb1)

// broadcast packed h pair p from lane 4p+1 (h2 = {h[2p],h[2p+1]} lives there)
#define RLH(p) const int hp_##p = rl_i(h2, 4 * p + 1);
// two dot2 per pair (rows rowA,rowB); 4 independent accumulator chains
#define MACP(p, A, B) { \
    const half2_t hh_##p = __builtin_bit_cast(half2_t, hp_##p); \
    A = FDOT2(__builtin_bit_cast(half2_t, wp0_##p), hh_##p, A); \
    B = FDOT2(__builtin_bit_cast(half2_t, wp1_##p), hh_##p, B); }

#define MAC_ALL \
    MACP(0,a0a,a1a) MACP(1,a0b,a1b) MACP(2,a0c,a1c) MACP(3,a0d,a1d) \
    MACP(4,a0a,a1a) MACP(5,a0b,a1b) MACP(6,a0c,a1c) MACP(7,a0d,a1d) \
    MACP(8,a0a,a1a) MACP(9,a0b,a1b) MACP(10,a0c,a1c) MACP(11,a0d,a1d) \
    MACP(12,a0a,a1a) MACP(13,a0b,a1b) MACP(14,a0c,a1c) MACP(15,a0d,a1d)

// One LSTM step consuming x row TU of buffers (XA,XB,XC). Updates c2/h/h2.
// DO_STAGE: statement executed with the fresh h (staging), or empty for warm.
#define STEP(XA, XB, XC, TU, DO_STAGE) do { \
    const float xs0 = rl_f(XA, TU), xs1 = rl_f(XB, TU), xs2 = rl_f(XC, TU); \
    REP16(RLH) \
    SCHED_FENCE(); \
    float a0a = fmaf(wi00, xs0, bb0); \
    float a0b = wi01 * xs1; \
    float a0c = wi02 * xs2; \
    float a0d = 0.0f; \
    float a1a = fmaf(wi10, xs0, bb1); \
    float a1b = wi11 * xs1; \
    float a1c = wi12 * xs2; \
    float a1d = 0.0f; \
    MAC_ALL \
    const float S0 = (a0a + a0b) + (a0c + a0d); \
    const float S1 = (a1a + a1b) + (a1c + a1d); \
    const float g0 = frcp(1.0f + FEXP2(S0));            /* sig(i) | sig(f) */ \
    const float rr = frcp(1.0f + FEXP2(S1)); \
    const float g1 = fmaf(rr, m1, d1);                  /* KN2*tanh(g) | sig(o) */ \
    const float igK = g0 * g1;                          /* even: KN2*i*g */ \
    const float t_ = dpp_xor1_f(igK);                   /* odd gets even's igK */ \
    c2 = fmaf(g0, c2, t_);                              /* odd: f*c2 + KN2*i*g */ \
    const float tc = fmaf(frcp(1.0f + FEXP2(c2)), 2.0f, -1.0f);  /* tanh(c) */ \
    h = g1 * tc;                                        /* odd: o * tanh(c) */ \
    const float hn = dpp_xor2_f(h); \
    h2 = pack_rtz(h, hn);                               /* f16 pair, lanes 4p+1 */ \
    DO_STAGE \
} while (0);

// ---- fused chunked scan + output GEMV, 2 waves/block, 16-step warm -----------
// Wave w of block b owns chunk cb = 2b+w. Chunks cb>0 warm up WARM=16 steps
// from (h,c)=(0,0) in a dedicated partial group, then run 2 live 64-step
// groups. Contraction: absmax was bit-identical (2^-9) across WARM=128/64/32
// (r9/r11/r14) => warm-32 error is far below the f16 quantization floor;
// Jacobian estimate rho_eff ~ 0.6/step (h-path gain ~||W_hh||*sigma' ~ 0.25,
// c-path f ~ 0.55) gives warm-16 error ~ 0.6^16*0.5 ~ 1.4e-4 << 6.9e-3.
// Empirical law (r10/r12/r13/r14): dispatch ~ 50.7us x (1 + WARM/CHUNK).
//
// r12 residency config: 128-thr blocks (2 waves), 40960 B LDS -> 4 blocks/CU
// = 2 waves/SIMD; waves_per_eu(1,2) (r11 lesson: max clamps residency).
// QUAD-LOCAL gate mapping (r8) + prescaled f16 weights + KN2-folded tanh.
// FUSED OUTPUT (r10): per-wave stage[64][33] (bank-clean), one coalesced
// 256 B store per 64 live steps.
__global__
__attribute__((amdgpu_flat_work_group_size(128, 128), amdgpu_waves_per_eu(1, 2)))
void lstm_scan(
    const float* __restrict__ x,      // [T,3]
    const float* __restrict__ W_ih,   // [128,3]
    const float* __restrict__ W_hh,   // [128,32]
    const float* __restrict__ b_ih,   // [128]
    const float* __restrict__ b_hh,   // [128]
    const float* __restrict__ W_lin,  // [1,32]
    const float* __restrict__ b_lin,  // [1]
    float* __restrict__ out)          // [T]
{
    // LDS = 16896 (2x stage) + 24064 (guard) = 40960 B -> 4 blocks/CU.
    __shared__ float stage[2][64 * 33];
    __shared__ float lds_guard[6016];
    ((volatile float*)lds_guard)[threadIdx.x] = 0.0f;

    const int wid = threadIdx.x >> 6;     // wave id within block (0,1)
    const int l = threadIdx.x & 63;       // lane 0..63
    const int u = l >> 1;
    const bool even = (l & 1) == 0;
    const int rowA = even ? u : (HID + u);                  // i_u | f_u (sigmoid)
    const int rowB = even ? (2 * HID + u) : (3 * HID + u);  // g_u | o_u
    const float sA = -L2E;
    const float sB = even ? KN2 : -L2E;
    const float m1 = even ? (2.0f * KN2) : 1.0f;
    const float d1 = even ? (-KN2) : 0.0f;

    REP16(DECLW)
    REP16(LOADW)

    float wi00 = W_ih[rowA * 3 + 0] * sA, wi01 = W_ih[rowA * 3 + 1] * sA,
          wi02 = W_ih[rowA * 3 + 2] * sA;
    float wi10 = W_ih[rowB * 3 + 0] * sB, wi11 = W_ih[rowB * 3 + 1] * sB,
          wi12 = W_ih[rowB * 3 + 2] * sB;
    float bb0 = (b_ih[rowA] + b_hh[rowA]) * sA;
    float bb1 = (b_ih[rowB] + b_hh[rowB]) * sB;

    const float wl = even ? 0.0f : W_lin[u];
    const float bl = b_lin[0];

    const int cb = blockIdx.x * 2 + wid;
    const int cstart = cb * CHUNK;

    float c2 = 0.0f;                  // c2 = KN2 * c (valid on odd lanes)
    float h = 0.0f;                   // valid on odd lanes
    int h2 = 0;                       // packed f16 pair, valid on lanes 4p+1
    float* mystage = &stage[wid][0];

    // ---- partial warm group: 16 steps, no stores (skipped for chunk 0) -----
    if (cb != 0) {
        const float* wp = x + (cstart - WARM + l) * 3;   // lanes 0..15 consumed
        float wa = wp[0], wb = wp[1], wc = wp[2];
        PIN_ALL
#pragma unroll 4
        for (int tu = 0; tu < WARM; ++tu) {
            STEP(wa, wb, wc, tu, )
        }
    }

    // ---- 2 live groups of 64 steps -----------------------------------------
    float xa, xb, xc;
    {
        const float* xp = x + (cstart + l) * 3;
        xa = xp[0]; xb = xp[1]; xc = xp[2];
    }

    for (int g = 0; g < 2; ++g) {
        PIN_ALL

        const int tn = (g == 0) ? (cstart + 64) : cstart;  // dummy on last
        const float* xp = x + (tn + l) * 3;
        float xna = xp[0], xnb = xp[1], xnc = xp[2];

#pragma unroll 4
        for (int tu = 0; tu < 64; ++tu) {
            STEP(xa, xb, xc, tu,
                 if (!even) { mystage[tu * 33 + u] = h * wl; })
        }

        // per-group output reduction + coalesced store
        {
            float s = bl;
            const float* row = &mystage[l * 33];        // banks (l+j)%32: clean
#pragma unroll
            for (int j = 0; j < HID; ++j) s += row[j];
            out[cstart + g * 64 + l] = s;               // 64 consecutive floats
        }

        xa = xna; xb = xnb; xc = xnc;
    }
}

extern "C" void kernel_launch(void* const* d_in, const int* in_sizes, int n_in,
                              void* d_out, int out_size, void* d_ws, size_t ws_size,
                              hipStream_t stream) {
    const float* x = (const float*)d_in[0];
    const float* W_ih = (const float*)d_in[1];
    const float* W_hh = (const float*)d_in[2];
    const float* b_ih = (const float*)d_in[3];
    const float* b_hh = (const float*)d_in[4];
    const float* W_lin = (const float*)d_in[5];
    const float* b_lin = (const float*)d_in[6];
    float* out = (float*)d_out;
    (void)d_ws; (void)ws_size;

    hipLaunchKernelGGL(lstm_scan, dim3(NBLK), dim3(128), 0, stream,
                       x, W_ih, W_hh, b_ih, b_hh, W_lin, b_lin, out);
}

// Round 16
// 117.725 us; speedup vs baseline: 1.1419x; 1.0059x over previous
//
#include <hip/hip_runtime.h>
#include <hip/hip_fp16.h>

#define T_LEN 262144
#define HID 32
#define CHUNK 128                 // live steps per wave
#define WARM 16                   // warm-up steps (err ~rho^16 ~ 1e-4, rho~0.6; r14/r15-verified)
#define NBLK (T_LEN / CHUNK / 2)  // 1024 blocks x 2 waves -> 2048 chunks

typedef _Float16 half2_t __attribute__((ext_vector_type(2)));

// ---- tiny intrinsic wrappers -------------------------------------------------
__device__ __forceinline__ float rl_f(float v, int lane) {
    return __int_as_float(__builtin_amdgcn_readlane(__float_as_int(v), lane));
}
__device__ __forceinline__ int rl_i(int v, int lane) {
    return __builtin_amdgcn_readlane(v, lane);
}

#if defined(__has_builtin)
#if __has_builtin(__builtin_amdgcn_exp2f)
#define FEXP2(x) __builtin_amdgcn_exp2f(x)
#endif
#endif
#ifndef FEXP2
#define FEXP2(x) exp2f(x)
#endif

__device__ __forceinline__ float frcp(float x) { return __builtin_amdgcn_rcpf(x); }

#if defined(__has_builtin)
#if __has_builtin(__builtin_amdgcn_sched_barrier)
#define SCHED_FENCE() __builtin_amdgcn_sched_barrier(0)
#endif
#endif
#ifndef SCHED_FENCE
#define SCHED_FENCE()
#endif

// packed 2×f16 MAC with f32 accumulate (v_dot2_f32_f16, full-rate VOP3P)
#if defined(__has_builtin) && __has_builtin(__builtin_amdgcn_fdot2)
#define FDOT2(a, b, c) __builtin_amdgcn_fdot2((a), (b), (c), false)
#else
#define FDOT2(a, b, c) fmaf((float)(a).x, (float)(b).x, \
                            fmaf((float)(a).y, (float)(b).y, (c)))
#endif

// quad_perm DPP cross-lane: full-rate VALU. [1,0,3,2]=0xB1 (lane^1), [2,3,0,1]=0x4E (lane^2)
__device__ __forceinline__ int dpp_xor1_i(int v) {
#if defined(__has_builtin) && __has_builtin(__builtin_amdgcn_mov_dpp)
    return __builtin_amdgcn_mov_dpp(v, 0xB1, 0xF, 0xF, true);
#else
    return __builtin_amdgcn_ds_swizzle(v, 0x041F);
#endif
}
__device__ __forceinline__ int dpp_xor2_i(int v) {
#if defined(__has_builtin) && __has_builtin(__builtin_amdgcn_mov_dpp)
    return __builtin_amdgcn_mov_dpp(v, 0x4E, 0xF, 0xF, true);
#else
    return __builtin_amdgcn_ds_swizzle(v, 0x081F);
#endif
}
__device__ __forceinline__ float dpp_xor1_f(float v) {
    return __int_as_float(dpp_xor1_i(__float_as_int(v)));
}
__device__ __forceinline__ float dpp_xor2_f(float v) {
    return __int_as_float(dpp_xor2_i(__float_as_int(v)));
}

// pack two f32 -> f16x2 in ONE instruction (v_cvt_pkrtz_f16_f32)
__device__ __forceinline__ int pack_rtz(float a, float b) {
#if defined(__has_builtin) && __has_builtin(__builtin_amdgcn_cvt_pkrtz)
    return __builtin_bit_cast(int, __builtin_amdgcn_cvt_pkrtz(a, b));
#else
    unsigned short ua = __builtin_bit_cast(unsigned short, (_Float16)a);
    unsigned short ub = __builtin_bit_cast(unsigned short, (_Float16)b);
    return (int)((unsigned int)ua | ((unsigned int)ub << 16));
#endif
}

#define L2E 1.4426950408889634f
#define KN2 (-2.0f * L2E)

// ---- repetition macros -------------------------------------------------------
#define REP16(M) M(0) M(1) M(2) M(3) M(4) M(5) M(6) M(7) \
                 M(8) M(9) M(10) M(11) M(12) M(13) M(14) M(15)

__device__ __forceinline__ unsigned int pack_f16(float a, float b) {
    unsigned short ua = __builtin_bit_cast(unsigned short, (_Float16)a);
    unsigned short ub = __builtin_bit_cast(unsigned short, (_Float16)b);
    return (unsigned int)ua | ((unsigned int)ub << 16);
}

// weight pair p: columns 2p,2p+1 of rows rowA / rowB, prescaled then f16-packed
#define DECLW(p) unsigned int wp0_##p, wp1_##p;
#define LOADW(p) \
    wp0_##p = pack_f16(W_hh[rowA * HID + 2 * p] * sA, W_hh[rowA * HID + 2 * p + 1] * sA); \
    wp1_##p = pack_f16(W_hh[rowB * HID + 2 * p] * sB, W_hh[rowB * HID + 2 * p + 1] * sB);

// Zero-instruction register pin (r3/r4 lesson): keeps the packed weights
// loop-carried in VGPRs under the raised RA budget.
#define PIN8(a,b,c,d,e,f,g,h_) \
    asm("" : "+v"(a), "+v"(b), "+v"(c), "+v"(d), \
             "+v"(e), "+v"(f), "+v"(g), "+v"(h_));
#define PIN_ALL \
    PIN8(wp0_0,wp0_1,wp0_2,wp0_3,wp0_4,wp0_5,wp0_6,wp0_7) \
    PIN8(wp0_8,wp0_9,wp0_10,wp0_11,wp0_12,wp0_13,wp0_14,wp0_15) \
    PIN8(wp1_0,wp1_1,wp1_2,wp1_3,wp1_4,wp1_5,wp1_6,wp1_7) \
    PIN8(wp1_8,wp1_9,wp1_10,wp1_11,wp1_12,wp1_13,wp1_14,wp1_15) \
    PIN8(wi00,wi01,wi02,wi10,wi11,wi12,bb0,bb1)

// broadcast packed h pair p from lane 4p+1 (h2 = {h[2p],h[2p+1]} lives there)
#define RLH(p) const int hp_##p = rl_i(h2, 4 * p + 1);
// two dot2 per pair (rows rowA,rowB); 4 independent accumulator chains
#define MACP(p, A, B) { \
    const half2_t hh_##p = __builtin_bit_cast(half2_t, hp_##p); \
    A = FDOT2(__builtin_bit_cast(half2_t, wp0_##p), hh_##p, A); \
    B = FDOT2(__builtin_bit_cast(half2_t, wp1_##p), hh_##p, B); }

#define MAC_ALL \
    MACP(0,a0a,a1a) MACP(1,a0b,a1b) MACP(2,a0c,a1c) MACP(3,a0d,a1d) \
    MACP(4,a0a,a1a) MACP(5,a0b,a1b) MACP(6,a0c,a1c) MACP(7,a0d,a1d) \
    MACP(8,a0a,a1a) MACP(9,a0b,a1b) MACP(10,a0c,a1c) MACP(11,a0d,a1d) \
    MACP(12,a0a,a1a) MACP(13,a0b,a1b) MACP(14,a0c,a1c) MACP(15,a0d,a1d)

// One LSTM step consuming x row TU of buffers (XA,XB,XC). Updates c2/h/h2.
// DO_STAGE: statement executed with the fresh h (staging), or empty for warm.
#define STEP(XA, XB, XC, TU, DO_STAGE) do { \
    const float xs0 = rl_f(XA, TU), xs1 = rl_f(XB, TU), xs2 = rl_f(XC, TU); \
    REP16(RLH) \
    SCHED_FENCE(); \
    float a0a = fmaf(wi00, xs0, bb0); \
    float a0b = wi01 * xs1; \
    float a0c = wi02 * xs2; \
    float a0d = 0.0f; \
    float a1a = fmaf(wi10, xs0, bb1); \
    float a1b = wi11 * xs1; \
    float a1c = wi12 * xs2; \
    float a1d = 0.0f; \
    MAC_ALL \
    const float S0 = (a0a + a0b) + (a0c + a0d); \
    const float S1 = (a1a + a1b) + (a1c + a1d); \
    const float g0 = frcp(1.0f + FEXP2(S0));            /* sig(i) | sig(f) */ \
    const float rr = frcp(1.0f + FEXP2(S1)); \
    const float g1 = fmaf(rr, m1, d1);                  /* KN2*tanh(g) | sig(o) */ \
    const float igK = g0 * g1;                          /* even: KN2*i*g */ \
    const float t_ = dpp_xor1_f(igK);                   /* odd gets even's igK */ \
    c2 = fmaf(g0, c2, t_);                              /* odd: f*c2 + KN2*i*g */ \
    const float tc = fmaf(frcp(1.0f + FEXP2(c2)), 2.0f, -1.0f);  /* tanh(c) */ \
    h = g1 * tc;                                        /* odd: o * tanh(c) */ \
    const float hn = dpp_xor2_f(h); \
    h2 = pack_rtz(h, hn);                               /* f16 pair, lanes 4p+1 */ \
    DO_STAGE \
} while (0);

// ---- fused chunked scan + output GEMV, 4 waves/SIMD --------------------------
// Wave w of block b owns chunk cb = 2b+w: WARM=16 warm steps from (h,c)=0
// (contraction, r14/r15-verified), then 2 live 64-step groups.
//
// r16 experiment: is the ~475 cy/chunk-step law (constant across 1 wave,
// 2 waves, dual-chunk — r10/r12/r13) VALU-issue-bound or shared-resource-
// bound? At 2 waves/SIMD VALUBusy=69% -> ~351 of 475 cy are real issue.
// Config: waves_per_eu(1,4) + LDS 20480 B -> 8 blocks/CU x 2 waves =
// 4 waves/SIMD. If issue-bound: VALUBusy -> ~90+, dispatch ~ -20%. If flat:
// the law is a hard shared-resource ceiling (readlane/SGPR port or trans
// arbitration) and we are at the practical floor.
// VGPR: budget at 4 waves/EU = 128 >= 88 used -> no spill expected.
//
// QUAD-LOCAL gate mapping (r8) + prescaled f16 weights + KN2-folded tanh.
// FUSED OUTPUT (r10): per-wave stage[64][33] (bank-clean), one coalesced
// 256 B store per 64 live steps.
__global__
__attribute__((amdgpu_flat_work_group_size(128, 128), amdgpu_waves_per_eu(1, 4)))
void lstm_scan(
    const float* __restrict__ x,      // [T,3]
    const float* __restrict__ W_ih,   // [128,3]
    const float* __restrict__ W_hh,   // [128,32]
    const float* __restrict__ b_ih,   // [128]
    const float* __restrict__ b_hh,   // [128]
    const float* __restrict__ W_lin,  // [1,32]
    const float* __restrict__ b_lin,  // [1]
    float* __restrict__ out)          // [T]
{
    // LDS = 16896 (2x stage) + 3584 (guard) = 20480 B -> 8 blocks/CU.
    __shared__ float stage[2][64 * 33];
    __shared__ float lds_guard[896];
    ((volatile float*)lds_guard)[threadIdx.x & 63] = 0.0f;

    const int wid = threadIdx.x >> 6;     // wave id within block (0,1)
    const int l = threadIdx.x & 63;       // lane 0..63
    const int u = l >> 1;
    const bool even = (l & 1) == 0;
    const int rowA = even ? u : (HID + u);                  // i_u | f_u (sigmoid)
    const int rowB = even ? (2 * HID + u) : (3 * HID + u);  // g_u | o_u
    const float sA = -L2E;
    const float sB = even ? KN2 : -L2E;
    const float m1 = even ? (2.0f * KN2) : 1.0f;
    const float d1 = even ? (-KN2) : 0.0f;

    REP16(DECLW)
    REP16(LOADW)

    float wi00 = W_ih[rowA * 3 + 0] * sA, wi01 = W_ih[rowA * 3 + 1] * sA,
          wi02 = W_ih[rowA * 3 + 2] * sA;
    float wi10 = W_ih[rowB * 3 + 0] * sB, wi11 = W_ih[rowB * 3 + 1] * sB,
          wi12 = W_ih[rowB * 3 + 2] * sB;
    float bb0 = (b_ih[rowA] + b_hh[rowA]) * sA;
    float bb1 = (b_ih[rowB] + b_hh[rowB]) * sB;

    const float wl = even ? 0.0f : W_lin[u];
    const float bl = b_lin[0];

    const int cb = blockIdx.x * 2 + wid;
    const int cstart = cb * CHUNK;

    float c2 = 0.0f;                  // c2 = KN2 * c (valid on odd lanes)
    float h = 0.0f;                   // valid on odd lanes
    int h2 = 0;                       // packed f16 pair, valid on lanes 4p+1
    float* mystage = &stage[wid][0];

    // ---- partial warm group: 16 steps, no stores (skipped for chunk 0) -----
    if (cb != 0) {
        const float* wp = x + (cstart - WARM + l) * 3;   // lanes 0..15 consumed
        float wa = wp[0], wb = wp[1], wc = wp[2];
        PIN_ALL
#pragma unroll 4
        for (int tu = 0; tu < WARM; ++tu) {
            STEP(wa, wb, wc, tu, )
        }
    }

    // ---- 2 live groups of 64 steps -----------------------------------------
    float xa, xb, xc;
    {
        const float* xp = x + (cstart + l) * 3;
        xa = xp[0]; xb = xp[1]; xc = xp[2];
    }

    for (int g = 0; g < 2; ++g) {
        PIN_ALL

        const int tn = (g == 0) ? (cstart + 64) : cstart;  // dummy on last
        const float* xp = x + (tn + l) * 3;
        float xna = xp[0], xnb = xp[1], xnc = xp[2];

#pragma unroll 4
        for (int tu = 0; tu < 64; ++tu) {
            STEP(xa, xb, xc, tu,
                 if (!even) { mystage[tu * 33 + u] = h * wl; })
        }

        // per-group output reduction + coalesced store
        {
            float s = bl;
            const float* row = &mystage[l * 33];        // banks (l+j)%32: clean
#pragma unroll
            for (int j = 0; j < HID; ++j) s += row[j];
            out[cstart + g * 64 + l] = s;               // 64 consecutive floats
        }

        xa = xna; xb = xnb; xc = xnc;
    }
}

extern "C" void kernel_launch(void* const* d_in, const int* in_sizes, int n_in,
                              void* d_out, int out_size, void* d_ws, size_t ws_size,
                              hipStream_t stream) {
    const float* x = (const float*)d_in[0];
    const float* W_ih = (const float*)d_in[1];
    const float* W_hh = (const float*)d_in[2];
    const float* b_ih = (const float*)d_in[3];
    const float* b_hh = (const float*)d_in[4];
    const float* W_lin = (const float*)d_in[5];
    const float* b_lin = (const float*)d_in[6];
    float* out = (float*)d_out;
    (void)d_ws; (void)ws_size;

    hipLaunchKernelGGL(lstm_scan, dim3(NBLK), dim3(128), 0, stream,
                       x, W_ih, W_hh, b_ih, b_hh, W_lin, b_lin, out);
}